// Round 1
// baseline (500.506 us; speedup 1.0000x reference)
//
#include <hip/hip_runtime.h>

typedef __bf16 bf16x8 __attribute__((ext_vector_type(8)));
typedef float f32x4 __attribute__((ext_vector_type(4)));
typedef unsigned short ushort_t;

// ---------- helpers ----------

__device__ __forceinline__ unsigned short f2bf(float f) {
    unsigned int u = __builtin_bit_cast(unsigned int, f);
    u += 0x7FFFu + ((u >> 16) & 1u);   // RNE (inputs are never NaN)
    return (unsigned short)(u >> 16);
}

__device__ __forceinline__ void async16(const void* g, void* l) {
    __builtin_amdgcn_global_load_lds(
        (const __attribute__((address_space(1))) void*)g,
        (__attribute__((address_space(3))) void*)l, 16, 0, 0);
}

#define MFMA16(a, b, c) __builtin_amdgcn_mfma_f32_16x16x32_bf16((a), (b), (c), 0, 0, 0)

// ---------- cast fp32 -> bf16 ----------

__global__ void __launch_bounds__(256)
castk(const float* __restrict__ in, ushort_t* __restrict__ out, int n8) {
    int i = blockIdx.x * blockDim.x + threadIdx.x;
    int stride = gridDim.x * blockDim.x;
    for (; i < n8; i += stride) {
        const float4* p = (const float4*)(in + (size_t)i * 8);
        float4 a = p[0], b = p[1];
        ushort_t r[8] = { f2bf(a.x), f2bf(a.y), f2bf(a.z), f2bf(a.w),
                          f2bf(b.x), f2bf(b.y), f2bf(b.z), f2bf(b.w) };
        *(uint4*)(out + (size_t)i * 8) = *(uint4*)r;
    }
}

// ---------- W [1024][1024] f32 -> W^T [n][k] bf16 ----------

__global__ void __launch_bounds__(256)
wtrans(const float* __restrict__ W, ushort_t* __restrict__ Wt) {
    __shared__ __attribute__((aligned(16))) float t[64][72];
    int k0 = blockIdx.x * 64, n0 = blockIdx.y * 64;
    int tid = threadIdx.x;
#pragma unroll
    for (int i = 0; i < 4; ++i) {
        int c = i * 256 + tid;          // 1024 float4 chunks
        int r = c >> 4, c4 = (c & 15) * 4;
        *(float4*)&t[r][c4] = *(const float4*)&W[(size_t)(k0 + r) * 1024 + n0 + c4];
    }
    __syncthreads();
#pragma unroll
    for (int i = 0; i < 2; ++i) {
        int c = i * 256 + tid;          // 512 chunks of 8 bf16
        int n = c & 63, kb = c >> 6;
        ushort_t tmp[8];
#pragma unroll
        for (int j = 0; j < 8; ++j) tmp[j] = f2bf(t[kb * 8 + j][n]);
        *(uint4*)&Wt[(size_t)(n0 + n) * 1024 + k0 + kb * 8] = *(uint4*)tmp;
    }
}

// ---------- V [bh][2048][64] -> V^T [bh][64][2048] (bf16) ----------

__global__ void __launch_bounds__(256)
vtrans(const ushort_t* __restrict__ V, ushort_t* __restrict__ Vt) {
    __shared__ __attribute__((aligned(16))) ushort_t t[64][80];
    int bh = blockIdx.x, st = blockIdx.y;
    const ushort_t* src = V + ((size_t)bh * 2048 + st * 64) * 64;
    int tid = threadIdx.x;
#pragma unroll
    for (int i = 0; i < 2; ++i) {
        int c = i * 256 + tid;          // 512 chunks of 8
        int r = c >> 3, col = (c & 7) * 8;
        *(uint4*)&t[r][col] = *(const uint4*)&src[(size_t)r * 64 + col];
    }
    __syncthreads();
    ushort_t* dst = Vt + (size_t)bh * 64 * 2048 + st * 64;
#pragma unroll
    for (int i = 0; i < 2; ++i) {
        int c = i * 256 + tid;
        int d = c & 63, sb = c >> 6;
        ushort_t tmp[8];
#pragma unroll
        for (int j = 0; j < 8; ++j) tmp[j] = t[sb * 8 + j][d];
        *(uint4*)&dst[(size_t)d * 2048 + sb * 8] = *(uint4*)tmp;
    }
}

// ---------- GEMM: C = A[M][K] * Bt[N][K]^T (+bias); 128x128 tile, BK=64 ----------
// MODE 0: bf16 out scattered to [B=4][H=16][S=2048][64], val=(acc+bias)*scale
// MODE 1: fp32 out [M][1024], val=acc+bias

template<int MODE>
__global__ void __launch_bounds__(256)
gemm_bt(const ushort_t* __restrict__ A, const ushort_t* __restrict__ Bt,
        const float* __restrict__ bias, void* __restrict__ Cout,
        int K, float scale) {
    __shared__ __attribute__((aligned(16))) ushort_t lA[128 * 64];
    __shared__ __attribute__((aligned(16))) ushort_t lB[128 * 64];
    const int tid = threadIdx.x;
    const int wave = tid >> 6, lane = tid & 63;
    const int lr = lane & 15, lg = lane >> 4;
    const int wm = wave >> 1, wn = wave & 1;
    const size_t m0 = (size_t)blockIdx.x * 128;
    const int n0 = blockIdx.y * 128;

    f32x4 acc[4][4] = {};

    const int nsteps = K / 64;
    for (int kt = 0; kt < nsteps; ++kt) {
        __syncthreads();
        // stage A,B: each 128x64 bf16 = 1024 16B chunks, inverse-swizzled source
#pragma unroll
        for (int i = 0; i < 4; ++i) {
            int c = i * 256 + tid;
            int r = c >> 3;
            int sc = (c & 7) ^ (r & 7);
            async16(A + (m0 + r) * K + kt * 64 + sc * 8, &lA[(i * 256 + wave * 64) * 8]);
        }
#pragma unroll
        for (int i = 0; i < 4; ++i) {
            int c = i * 256 + tid;
            int r = c >> 3;
            int sc = (c & 7) ^ (r & 7);
            async16(Bt + (size_t)(n0 + r) * K + kt * 64 + sc * 8, &lB[(i * 256 + wave * 64) * 8]);
        }
        __syncthreads();
#pragma unroll
        for (int kc = 0; kc < 2; ++kc) {
            bf16x8 af[4], bfr[4];
#pragma unroll
            for (int t = 0; t < 4; ++t) {
                int rowA = wm * 64 + t * 16 + lr;
                int byteA = (rowA * 128 + (kc * 32 + lg * 8) * 2) ^ ((rowA & 7) << 4);
                af[t] = *(const bf16x8*)((const char*)lA + byteA);
                int rowB = wn * 64 + t * 16 + lr;
                int byteB = (rowB * 128 + (kc * 32 + lg * 8) * 2) ^ ((rowB & 7) << 4);
                bfr[t] = *(const bf16x8*)((const char*)lB + byteB);
            }
#pragma unroll
            for (int i = 0; i < 4; ++i)
#pragma unroll
                for (int j = 0; j < 4; ++j)
                    acc[i][j] = MFMA16(af[i], bfr[j], acc[i][j]);
        }
    }

    float bv[4];
#pragma unroll
    for (int nt = 0; nt < 4; ++nt) bv[nt] = bias[n0 + wn * 64 + nt * 16 + lr];

    if (MODE == 0) {
        ushort_t* dst = (ushort_t*)Cout;
#pragma unroll
        for (int mt = 0; mt < 4; ++mt)
#pragma unroll
            for (int nt = 0; nt < 4; ++nt)
#pragma unroll
                for (int j = 0; j < 4; ++j) {
                    size_t m = m0 + wm * 64 + mt * 16 + lg * 4 + j;
                    int n = n0 + wn * 64 + nt * 16 + lr;
                    size_t b = m >> 11, s = m & 2047;
                    int h = n >> 6, dk = n & 63;
                    float v = (acc[mt][nt][j] + bv[nt]) * scale;
                    dst[((b * 16 + h) * 2048 + s) * 64 + dk] = f2bf(v);
                }
    } else {
        float* dst = (float*)Cout;
#pragma unroll
        for (int mt = 0; mt < 4; ++mt)
#pragma unroll
            for (int nt = 0; nt < 4; ++nt)
#pragma unroll
                for (int j = 0; j < 4; ++j) {
                    size_t m = m0 + wm * 64 + mt * 16 + lg * 4 + j;
                    int n = n0 + wn * 64 + nt * 16 + lr;
                    dst[m * 1024 + n] = acc[mt][nt][j] + bv[nt];
                }
    }
}

// ---------- flash attention: Q[bh][2048][64] (pre-scaled), K[bh][2048][64], Vt[bh][64][2048] ----------
// out X: [B][S][H][64] bf16.  Block: 4 waves x 32 q-rows = 128 q-rows; KVBLK=64.

__global__ void __launch_bounds__(256)
attn(const ushort_t* __restrict__ Q, const ushort_t* __restrict__ Kb,
     const ushort_t* __restrict__ Vt, ushort_t* __restrict__ X) {
    __shared__ __attribute__((aligned(16))) ushort_t lK[64 * 64];
    __shared__ __attribute__((aligned(16))) ushort_t lV[64 * 64];
    __shared__ __attribute__((aligned(16))) ushort_t lP[4][32 * 64];
    const int tid = threadIdx.x, wave = tid >> 6, lane = tid & 63;
    const int lr = lane & 15, lg = lane >> 4;
    const int bh = blockIdx.x;
    const int q0 = blockIdx.y * 128 + wave * 32;

    // Q fragments hoisted to registers (whole kernel)
    const ushort_t* Qg = Q + ((size_t)bh * 2048 + q0) * 64;
    bf16x8 qf[2][2];
#pragma unroll
    for (int mt = 0; mt < 2; ++mt)
#pragma unroll
        for (int kc = 0; kc < 2; ++kc)
            qf[mt][kc] = *(const bf16x8*)&Qg[(mt * 16 + lr) * 64 + kc * 32 + lg * 8];

    f32x4 oacc[2][4] = {};
    float mrun[2][4], lrun[2][4];
#pragma unroll
    for (int mt = 0; mt < 2; ++mt)
#pragma unroll
        for (int j = 0; j < 4; ++j) { mrun[mt][j] = -1e30f; lrun[mt][j] = 0.f; }

    for (int kv0 = 0; kv0 < 2048; kv0 += 64) {
        __syncthreads();
        const ushort_t* Kg = Kb + ((size_t)bh * 2048 + kv0) * 64;
        const ushort_t* Vg = Vt + (size_t)bh * 64 * 2048 + kv0;
#pragma unroll
        for (int i = 0; i < 2; ++i) {
            int c = i * 256 + tid;
            int r = c >> 3, sc = (c & 7) ^ (r & 7);
            async16(Kg + (size_t)r * 64 + sc * 8, &lK[(i * 256 + wave * 64) * 8]);
        }
#pragma unroll
        for (int i = 0; i < 2; ++i) {
            int c = i * 256 + tid;
            int r = c >> 3, sc = (c & 7) ^ (r & 7);
            async16(Vg + (size_t)r * 2048 + sc * 8, &lV[(i * 256 + wave * 64) * 8]);
        }
        __syncthreads();

        // S = Q K^T   (D layout: col=kv=lane&15 (+16*nt), row=q=(lane>>4)*4+j (+16*mt))
        f32x4 s[2][4] = {};
#pragma unroll
        for (int kc = 0; kc < 2; ++kc)
#pragma unroll
            for (int nt = 0; nt < 4; ++nt) {
                int rowK = nt * 16 + lr;
                int byteK = (rowK * 128 + (kc * 32 + lg * 8) * 2) ^ ((rowK & 7) << 4);
                bf16x8 kf = *(const bf16x8*)((const char*)lK + byteK);
                s[0][nt] = MFMA16(qf[0][kc], kf, s[0][nt]);
                s[1][nt] = MFMA16(qf[1][kc], kf, s[1][nt]);
            }

        // online softmax
#pragma unroll
        for (int mt = 0; mt < 2; ++mt)
#pragma unroll
            for (int j = 0; j < 4; ++j) {
                float mx = fmaxf(fmaxf(s[mt][0][j], s[mt][1][j]),
                                 fmaxf(s[mt][2][j], s[mt][3][j]));
                mx = fmaxf(mx, __shfl_xor(mx, 1));
                mx = fmaxf(mx, __shfl_xor(mx, 2));
                mx = fmaxf(mx, __shfl_xor(mx, 4));
                mx = fmaxf(mx, __shfl_xor(mx, 8));
                float mnew = fmaxf(mrun[mt][j], mx);
                float scl = __expf(mrun[mt][j] - mnew);
                mrun[mt][j] = mnew;
                float rs = 0.f;
#pragma unroll
                for (int nt = 0; nt < 4; ++nt) {
                    float e = __expf(s[mt][nt][j] - mnew);
                    s[mt][nt][j] = e;
                    rs += e;
                }
                rs += __shfl_xor(rs, 1);
                rs += __shfl_xor(rs, 2);
                rs += __shfl_xor(rs, 4);
                rs += __shfl_xor(rs, 8);
                lrun[mt][j] = lrun[mt][j] * scl + rs;
#pragma unroll
                for (int nt = 0; nt < 4; ++nt) oacc[mt][nt][j] *= scl;
            }

        // P -> per-wave LDS (swizzled), then PV
#pragma unroll
        for (int mt = 0; mt < 2; ++mt)
#pragma unroll
            for (int nt = 0; nt < 4; ++nt)
#pragma unroll
                for (int j = 0; j < 4; ++j) {
                    int r = mt * 16 + lg * 4 + j;
                    int byte = (r * 128 + (nt * 16 + lr) * 2) ^ ((r & 7) << 4);
                    *(ushort_t*)((char*)&lP[wave][0] + byte) = f2bf(s[mt][nt][j]);
                }
        asm volatile("s_waitcnt lgkmcnt(0)" ::: "memory");

#pragma unroll
        for (int kc = 0; kc < 2; ++kc) {
            bf16x8 pf[2];
#pragma unroll
            for (int mt = 0; mt < 2; ++mt) {
                int r = mt * 16 + lr;
                int byte = (r * 128 + (kc * 32 + lg * 8) * 2) ^ ((r & 7) << 4);
                pf[mt] = *(const bf16x8*)((const char*)&lP[wave][0] + byte);
            }
#pragma unroll
            for (int nt = 0; nt < 4; ++nt) {
                int rowV = nt * 16 + lr;
                int byteV = (rowV * 128 + (kc * 32 + lg * 8) * 2) ^ ((rowV & 7) << 4);
                bf16x8 vf = *(const bf16x8*)((const char*)lV + byteV);
                oacc[0][nt] = MFMA16(pf[0], vf, oacc[0][nt]);
                oacc[1][nt] = MFMA16(pf[1], vf, oacc[1][nt]);
            }
        }
    }

    // epilogue: X[((b*2048+q)*16+h)*64 + d]
    const int b = bh >> 4, h = bh & 15;
#pragma unroll
    for (int mt = 0; mt < 2; ++mt)
#pragma unroll
        for (int j = 0; j < 4; ++j) {
            int q = q0 + mt * 16 + lg * 4 + j;
            float inv = 1.f / lrun[mt][j];
            ushort_t* dst = X + (((size_t)b * 2048 + q) * 16 + h) * 64;
#pragma unroll
            for (int nt = 0; nt < 4; ++nt)
                dst[nt * 16 + lr] = f2bf(oacc[mt][nt][j] * inv);
        }
}

// ---------- launcher ----------

extern "C" void kernel_launch(void* const* d_in, const int* in_sizes, int n_in,
                              void* d_out, int out_size, void* d_ws, size_t ws_size,
                              hipStream_t stream) {
    const float* query = (const float*)d_in[0];
    const float* key   = (const float*)d_in[1];
    const float* value = (const float*)d_in[2];
    const float* Wq = (const float*)d_in[3];
    const float* bq = (const float*)d_in[4];
    const float* Wk = (const float*)d_in[5];
    const float* bk = (const float*)d_in[6];
    const float* Wv = (const float*)d_in[7];
    const float* bv = (const float*)d_in[8];
    const float* Wo = (const float*)d_in[9];
    const float* bo = (const float*)d_in[10];
    float* out = (float*)d_out;

    char* ws = (char*)d_ws;
    const size_t MB = 1024 * 1024;
    ushort_t* Wqt = (ushort_t*)(ws + 0 * MB);
    ushort_t* Wkt = (ushort_t*)(ws + 2 * MB);
    ushort_t* Wvt = (ushort_t*)(ws + 4 * MB);
    ushort_t* Wot = (ushort_t*)(ws + 6 * MB);
    ushort_t* Xq  = (ushort_t*)(ws + 8 * MB);   // cast(query); later aliased by V^T
    ushort_t* Xk  = (ushort_t*)(ws + 24 * MB);  // cast(key);   later aliased by X(attn out)
    ushort_t* Xv  = (ushort_t*)(ws + 40 * MB);  // cast(value)
    ushort_t* Qp  = (ushort_t*)(ws + 56 * MB);
    ushort_t* Kp  = (ushort_t*)(ws + 72 * MB);
    ushort_t* Vp  = (ushort_t*)(ws + 88 * MB);  // total 104 MB
    ushort_t* Vtp = Xq;   // safe: casts dead after projections
    ushort_t* Xat = Xk;

    const int n8 = 8192 * 1024 / 8;
    castk<<<dim3(1024), dim3(256), 0, stream>>>(query, Xq, n8);
    castk<<<dim3(1024), dim3(256), 0, stream>>>(key, Xk, n8);
    castk<<<dim3(1024), dim3(256), 0, stream>>>(value, Xv, n8);

    wtrans<<<dim3(16, 16), dim3(256), 0, stream>>>(Wq, Wqt);
    wtrans<<<dim3(16, 16), dim3(256), 0, stream>>>(Wk, Wkt);
    wtrans<<<dim3(16, 16), dim3(256), 0, stream>>>(Wv, Wvt);
    wtrans<<<dim3(16, 16), dim3(256), 0, stream>>>(Wo, Wot);

    const float qscale = 0.125f;  // 1/sqrt(64)
    gemm_bt<0><<<dim3(64, 8), dim3(256), 0, stream>>>(Xq, Wqt, bq, Qp, 1024, qscale);
    gemm_bt<0><<<dim3(64, 8), dim3(256), 0, stream>>>(Xk, Wkt, bk, Kp, 1024, 1.f);
    gemm_bt<0><<<dim3(64, 8), dim3(256), 0, stream>>>(Xv, Wvt, bv, Vp, 1024, 1.f);

    vtrans<<<dim3(64, 32), dim3(256), 0, stream>>>(Vp, Vtp);

    attn<<<dim3(64, 16), dim3(256), 0, stream>>>(Qp, Kp, Vtp, Xat);

    gemm_bt<1><<<dim3(64, 8), dim3(256), 0, stream>>>(Xat, Wot, bo, out, 1024, 1.f);
}

// Round 4
// 374.211 us; speedup vs baseline: 1.3375x; 1.3375x over previous
//
#include <hip/hip_runtime.h>

typedef __bf16 bf16x8 __attribute__((ext_vector_type(8)));
typedef float f32x4 __attribute__((ext_vector_type(4)));
typedef float f32x16 __attribute__((ext_vector_type(16)));
typedef unsigned int u32x4v __attribute__((ext_vector_type(4)));
typedef unsigned short ushort_t;

// ---------- helpers ----------

__device__ __forceinline__ unsigned short f2bf(float f) {
    unsigned int u = __builtin_bit_cast(unsigned int, f);
    u += 0x7FFFu + ((u >> 16) & 1u);   // RNE (inputs are never NaN)
    return (unsigned short)(u >> 16);
}

__device__ __forceinline__ unsigned int cvtpk(float lo, float hi) {
    unsigned int r;
    asm("v_cvt_pk_bf16_f32 %0, %1, %2" : "=v"(r) : "v"(lo), "v"(hi));
    return r;
}

__device__ __forceinline__ void async16(const void* g, void* l) {
    __builtin_amdgcn_global_load_lds(
        (const __attribute__((address_space(1))) void*)g,
        (__attribute__((address_space(3))) void*)l, 16, 0, 0);
}

#define MFMA16(a, b, c) __builtin_amdgcn_mfma_f32_16x16x32_bf16((a), (b), (c), 0, 0, 0)
#define MFMA32(a, b, c) __builtin_amdgcn_mfma_f32_32x32x16_bf16((a), (b), (c), 0, 0, 0)

// ---------- cast fp32 -> bf16 (q,k,v fused) ----------

__global__ void __launch_bounds__(256)
castk3(const float* __restrict__ a, const float* __restrict__ b, const float* __restrict__ c,
       ushort_t* __restrict__ oa, ushort_t* __restrict__ ob, ushort_t* __restrict__ oc, int n8) {
    int i = blockIdx.x * blockDim.x + threadIdx.x;
    int stride = gridDim.x * blockDim.x;
    for (; i < 3 * n8; i += stride) {
        const float* in; ushort_t* out; int j = i;
        if (j < n8)            { in = a; out = oa; }
        else if (j < 2 * n8)   { in = b; out = ob; j -= n8; }
        else                   { in = c; out = oc; j -= 2 * n8; }
        const float4* p = (const float4*)(in + (size_t)j * 8);
        float4 x = p[0], y = p[1];
        ushort_t r[8] = { f2bf(x.x), f2bf(x.y), f2bf(x.z), f2bf(x.w),
                          f2bf(y.x), f2bf(y.y), f2bf(y.z), f2bf(y.w) };
        *(uint4*)(out + (size_t)j * 8) = *(uint4*)r;
    }
}

// ---------- W [1024][1024] f32 -> W^T [n][k] bf16, 4 weights in one launch ----------

__global__ void __launch_bounds__(256)
wtrans4(const float* __restrict__ W0, const float* __restrict__ W1,
        const float* __restrict__ W2, const float* __restrict__ W3,
        ushort_t* __restrict__ T0, ushort_t* __restrict__ T1,
        ushort_t* __restrict__ T2, ushort_t* __restrict__ T3) {
    __shared__ __attribute__((aligned(16))) float t[64][72];
    int z = blockIdx.z;
    const float* W = z == 0 ? W0 : z == 1 ? W1 : z == 2 ? W2 : W3;
    ushort_t* Wt   = z == 0 ? T0 : z == 1 ? T1 : z == 2 ? T2 : T3;
    int k0 = blockIdx.x * 64, n0 = blockIdx.y * 64;
    int tid = threadIdx.x;
#pragma unroll
    for (int i = 0; i < 4; ++i) {
        int ci = i * 256 + tid;
        int r = ci >> 4, c4 = (ci & 15) * 4;
        *(float4*)&t[r][c4] = *(const float4*)&W[(size_t)(k0 + r) * 1024 + n0 + c4];
    }
    __syncthreads();
#pragma unroll
    for (int i = 0; i < 2; ++i) {
        int ci = i * 256 + tid;
        int n = ci & 63, kb = ci >> 6;
        ushort_t tmp[8];
#pragma unroll
        for (int j = 0; j < 8; ++j) tmp[j] = f2bf(t[kb * 8 + j][n]);
        *(uint4*)&Wt[(size_t)(n0 + n) * 1024 + k0 + kb * 8] = *(uint4*)tmp;
    }
}

// ---------- V [bh][2048][64] -> V^T [bh][64][2048] (bf16) ----------

__global__ void __launch_bounds__(256)
vtrans(const ushort_t* __restrict__ V, ushort_t* __restrict__ Vt) {
    __shared__ __attribute__((aligned(16))) ushort_t t[64][80];
    int bh = blockIdx.x, st = blockIdx.y;
    const ushort_t* src = V + ((size_t)bh * 2048 + st * 64) * 64;
    int tid = threadIdx.x;
#pragma unroll
    for (int i = 0; i < 2; ++i) {
        int c = i * 256 + tid;
        int r = c >> 3, col = (c & 7) * 8;
        *(uint4*)&t[r][col] = *(const uint4*)&src[(size_t)r * 64 + col];
    }
    __syncthreads();
    ushort_t* dst = Vt + (size_t)bh * 64 * 2048 + st * 64;
#pragma unroll
    for (int i = 0; i < 2; ++i) {
        int c = i * 256 + tid;
        int d = c & 63, sb = c >> 6;
        ushort_t tmp[8];
#pragma unroll
        for (int j = 0; j < 8; ++j) tmp[j] = t[sb * 8 + j][d];
        *(uint4*)&dst[(size_t)d * 2048 + sb * 8] = *(uint4*)tmp;
    }
}

// ---------- fused QKV projection: 3 GEMMs in one launch ----------
// blockIdx.y: 0..23 -> sel = y>>3 chooses (A, W, bias, dst, scale)
// C scattered to [B=4][H=16][S=2048][64] bf16

__global__ void __launch_bounds__(256)
proj_qkv(const ushort_t* __restrict__ Xq, const ushort_t* __restrict__ Xk,
         const ushort_t* __restrict__ Xv, const ushort_t* __restrict__ Wt,
         const float* __restrict__ bqp, const float* __restrict__ bkp,
         const float* __restrict__ bvp,
         ushort_t* __restrict__ Qp, ushort_t* __restrict__ Kp, ushort_t* __restrict__ Vp) {
    __shared__ __attribute__((aligned(16))) ushort_t lA[128 * 64];
    __shared__ __attribute__((aligned(16))) ushort_t lB[128 * 64];
    const int tid = threadIdx.x;
    const int wave = tid >> 6, lane = tid & 63;
    const int lr = lane & 15, lg = lane >> 4;
    const int wm = wave >> 1, wn = wave & 1;
    const size_t m0 = (size_t)blockIdx.x * 128;
    const int sel = blockIdx.y >> 3;
    const int n0 = (blockIdx.y & 7) * 128;

    const ushort_t* A    = sel == 0 ? Xq : sel == 1 ? Xk : Xv;
    const ushort_t* Bt   = Wt + (size_t)sel * 1024 * 1024;
    const float*    bias = sel == 0 ? bqp : sel == 1 ? bkp : bvp;
    ushort_t*       dst  = sel == 0 ? Qp : sel == 1 ? Kp : Vp;
    const float     scale = sel == 0 ? 0.125f : 1.0f;

    f32x4 acc[4][4] = {};

    for (int kt = 0; kt < 16; ++kt) {
        __syncthreads();
#pragma unroll
        for (int i = 0; i < 4; ++i) {
            int c = i * 256 + tid;
            int r = c >> 3;
            int sc = (c & 7) ^ (r & 7);
            async16(A + (m0 + r) * 1024 + kt * 64 + sc * 8, &lA[(i * 256 + wave * 64) * 8]);
        }
#pragma unroll
        for (int i = 0; i < 4; ++i) {
            int c = i * 256 + tid;
            int r = c >> 3;
            int sc = (c & 7) ^ (r & 7);
            async16(Bt + (size_t)(n0 + r) * 1024 + kt * 64 + sc * 8, &lB[(i * 256 + wave * 64) * 8]);
        }
        __syncthreads();
#pragma unroll
        for (int kc = 0; kc < 2; ++kc) {
            bf16x8 af[4], bfr[4];
#pragma unroll
            for (int t = 0; t < 4; ++t) {
                int rowA = wm * 64 + t * 16 + lr;
                int byteA = (rowA * 128 + (kc * 32 + lg * 8) * 2) ^ ((rowA & 7) << 4);
                af[t] = *(const bf16x8*)((const char*)lA + byteA);
                int rowB = wn * 64 + t * 16 + lr;
                int byteB = (rowB * 128 + (kc * 32 + lg * 8) * 2) ^ ((rowB & 7) << 4);
                bfr[t] = *(const bf16x8*)((const char*)lB + byteB);
            }
#pragma unroll
            for (int i = 0; i < 4; ++i)
#pragma unroll
                for (int j = 0; j < 4; ++j)
                    acc[i][j] = MFMA16(af[i], bfr[j], acc[i][j]);
        }
    }

    float bv[4];
#pragma unroll
    for (int nt = 0; nt < 4; ++nt) bv[nt] = bias[n0 + wn * 64 + nt * 16 + lr];

#pragma unroll
    for (int mt = 0; mt < 4; ++mt)
#pragma unroll
        for (int nt = 0; nt < 4; ++nt)
#pragma unroll
            for (int j = 0; j < 4; ++j) {
                size_t m = m0 + wm * 64 + mt * 16 + lg * 4 + j;
                int n = n0 + wn * 64 + nt * 16 + lr;
                size_t b = m >> 11, s = m & 2047;
                int h = n >> 6, dk = n & 63;
                float v = (acc[mt][nt][j] + bv[nt]) * scale;
                dst[((b * 16 + h) * 2048 + s) * 64 + dk] = f2bf(v);
            }
}

// ---------- output projection GEMM: fp32 out [M][1024] ----------

__global__ void __launch_bounds__(256)
gemm_out(const ushort_t* __restrict__ A, const ushort_t* __restrict__ Bt,
         const float* __restrict__ bias, float* __restrict__ dst) {
    __shared__ __attribute__((aligned(16))) ushort_t lA[128 * 64];
    __shared__ __attribute__((aligned(16))) ushort_t lB[128 * 64];
    const int tid = threadIdx.x;
    const int wave = tid >> 6, lane = tid & 63;
    const int lr = lane & 15, lg = lane >> 4;
    const int wm = wave >> 1, wn = wave & 1;
    const size_t m0 = (size_t)blockIdx.x * 128;
    const int n0 = blockIdx.y * 128;

    f32x4 acc[4][4] = {};

    for (int kt = 0; kt < 16; ++kt) {
        __syncthreads();
#pragma unroll
        for (int i = 0; i < 4; ++i) {
            int c = i * 256 + tid;
            int r = c >> 3;
            int sc = (c & 7) ^ (r & 7);
            async16(A + (m0 + r) * 1024 + kt * 64 + sc * 8, &lA[(i * 256 + wave * 64) * 8]);
        }
#pragma unroll
        for (int i = 0; i < 4; ++i) {
            int c = i * 256 + tid;
            int r = c >> 3;
            int sc = (c & 7) ^ (r & 7);
            async16(Bt + (size_t)(n0 + r) * 1024 + kt * 64 + sc * 8, &lB[(i * 256 + wave * 64) * 8]);
        }
        __syncthreads();
#pragma unroll
        for (int kc = 0; kc < 2; ++kc) {
            bf16x8 af[4], bfr[4];
#pragma unroll
            for (int t = 0; t < 4; ++t) {
                int rowA = wm * 64 + t * 16 + lr;
                int byteA = (rowA * 128 + (kc * 32 + lg * 8) * 2) ^ ((rowA & 7) << 4);
                af[t] = *(const bf16x8*)((const char*)lA + byteA);
                int rowB = wn * 64 + t * 16 + lr;
                int byteB = (rowB * 128 + (kc * 32 + lg * 8) * 2) ^ ((rowB & 7) << 4);
                bfr[t] = *(const bf16x8*)((const char*)lB + byteB);
            }
#pragma unroll
            for (int i = 0; i < 4; ++i)
#pragma unroll
                for (int j = 0; j < 4; ++j)
                    acc[i][j] = MFMA16(af[i], bfr[j], acc[i][j]);
        }
    }

    float bv[4];
#pragma unroll
    for (int nt = 0; nt < 4; ++nt) bv[nt] = bias[n0 + wn * 64 + nt * 16 + lr];

#pragma unroll
    for (int mt = 0; mt < 4; ++mt)
#pragma unroll
        for (int nt = 0; nt < 4; ++nt)
#pragma unroll
            for (int j = 0; j < 4; ++j) {
                size_t m = m0 + wm * 64 + mt * 16 + lg * 4 + j;
                int n = n0 + wn * 64 + nt * 16 + lr;
                dst[m * 1024 + n] = acc[mt][nt][j] + bv[nt];
            }
}

// ---------- flash attention, swapped-operand form ----------
// Q[bh][2048][64] pre-scaled, K[bh][2048][64], Vt[bh][64][2048]; out X [B][S][H][64] bf16.
// 4 waves x 32 q-rows; KVBLK=64. Lane owns q = lane&31 (pair l, l^32 split kv).
// S^T = mfma32(K, Q^T): C col = q, rows = kv.  O^T = mfma32(V^T, P^T): col = q, rows = d.

__global__ void __launch_bounds__(256)
attn(const ushort_t* __restrict__ Q, const ushort_t* __restrict__ Kb,
     const ushort_t* __restrict__ Vt, ushort_t* __restrict__ X) {
    __shared__ __attribute__((aligned(16))) ushort_t lK[64 * 64];
    __shared__ __attribute__((aligned(16))) ushort_t lV[64 * 64];
    const int tid = threadIdx.x, wave = tid >> 6, lane = tid & 63;
    const int ql = lane & 31, hi = lane >> 5;
    const int bh = blockIdx.x;
    const int q0 = blockIdx.y * 128 + wave * 32;

    // Q fragments (B-operand of 32x32x16): lane holds Q[q0+ql][dk*16 + hi*8 + j]
    const ushort_t* Qg = Q + ((size_t)bh * 2048 + q0 + ql) * 64 + hi * 8;
    bf16x8 qf[4];
#pragma unroll
    for (int dk = 0; dk < 4; ++dk) qf[dk] = *(const bf16x8*)(Qg + dk * 16);

    // precomputed swizzled LDS addressing (row = {ql, 32+ql}; rx identical for both)
    const int rx = ql & 7;
    int off[4];
#pragma unroll
    for (int dk = 0; dk < 4; ++dk) off[dk] = ((dk * 2 + hi) ^ rx) * 16;
    const char* kB0 = (const char*)lK + ql * 128;
    const char* kB1 = kB0 + 32 * 128;
    const char* vB0 = (const char*)lV + ql * 128;
    const char* vB1 = vB0 + 32 * 128;

    // staging addressing (2 chunks each of K and V per thread)
    int sr[2], ssc[2];
#pragma unroll
    for (int i = 0; i < 2; ++i) {
        int c = i * 256 + tid;
        sr[i] = c >> 3;
        ssc[i] = (c & 7) ^ (sr[i] & 7);
    }
    const ushort_t* Kroot = Kb + (size_t)bh * 2048 * 64;
    const ushort_t* Vroot = Vt + (size_t)bh * 64 * 2048;

    f32x16 oa0 = {}, oa1 = {};
    float mrun = -1e30f, lrun = 0.f;

    for (int kv0 = 0; kv0 < 2048; kv0 += 64) {
        __syncthreads();
#pragma unroll
        for (int i = 0; i < 2; ++i)
            async16(Kroot + (size_t)(kv0 + sr[i]) * 64 + ssc[i] * 8,
                    &lK[(i * 256 + wave * 64) * 8]);
#pragma unroll
        for (int i = 0; i < 2; ++i)
            async16(Vroot + (size_t)sr[i] * 2048 + kv0 + ssc[i] * 8,
                    &lV[(i * 256 + wave * 64) * 8]);
        __syncthreads();

        // S^T: st0 = kv rows [0,32), st1 = [32,64); col = q
        f32x16 st0 = {}, st1 = {};
#pragma unroll
        for (int dk = 0; dk < 4; ++dk) {
            bf16x8 k0 = *(const bf16x8*)(kB0 + off[dk]);
            bf16x8 k1 = *(const bf16x8*)(kB1 + off[dk]);
            st0 = MFMA32(k0, qf[dk], st0);
            st1 = MFMA32(k1, qf[dk], st1);
        }

        // online softmax — row (q) is lane-local; pair over hi via shfl_xor 32
        float mloc = st0[0];
#pragma unroll
        for (int r = 1; r < 16; ++r) mloc = fmaxf(mloc, st0[r]);
#pragma unroll
        for (int r = 0; r < 16; ++r) mloc = fmaxf(mloc, st1[r]);
        float mx = fmaxf(mloc, __shfl_xor(mloc, 32));
        float mnew = fmaxf(mrun, mx);
        float scl = __expf(mrun - mnew);
        mrun = mnew;
        float ps = 0.f;
#pragma unroll
        for (int r = 0; r < 16; ++r) { float e = __expf(st0[r] - mnew); st0[r] = e; ps += e; }
#pragma unroll
        for (int r = 0; r < 16; ++r) { float e = __expf(st1[r] - mnew); st1[r] = e; ps += e; }
        lrun = lrun * scl + ps;
#pragma unroll
        for (int r = 0; r < 16; ++r) { oa0[r] *= scl; oa1[r] *= scl; }

        // pack P^T into B-operand fragments: 16 cvt_pk + 8 permlane32_swap
        bf16x8 pb[4];
#pragma unroll
        for (int ks = 0; ks < 4; ++ks) {
            int rb = (ks & 1) * 8;
            unsigned int A_, B_, C_, D_;
            if (ks < 2) {
                A_ = cvtpk(st0[rb + 0], st0[rb + 1]);
                B_ = cvtpk(st0[rb + 4], st0[rb + 5]);
                C_ = cvtpk(st0[rb + 2], st0[rb + 3]);
                D_ = cvtpk(st0[rb + 6], st0[rb + 7]);
            } else {
                A_ = cvtpk(st1[rb + 0], st1[rb + 1]);
                B_ = cvtpk(st1[rb + 4], st1[rb + 5]);
                C_ = cvtpk(st1[rb + 2], st1[rb + 3]);
                D_ = cvtpk(st1[rb + 6], st1[rb + 7]);
            }
            // exchange upper(A)<->lower(B): result A holds k-pair (j0,j1), B holds (j4,j5)
            asm("v_permlane32_swap_b32 %0, %1" : "+v"(A_), "+v"(B_));
            asm("v_permlane32_swap_b32 %0, %1" : "+v"(C_), "+v"(D_));
            u32x4v w = { A_, C_, B_, D_ };
            pb[ks] = __builtin_bit_cast(bf16x8, w);
        }

        // O^T += V^T · P^T  (A = V^T frag from LDS, B = pb)
#pragma unroll
        for (int ks = 0; ks < 4; ++ks) {
            bf16x8 v0 = *(const bf16x8*)(vB0 + off[ks]);
            bf16x8 v1 = *(const bf16x8*)(vB1 + off[ks]);
            oa0 = MFMA32(v0, pb[ks], oa0);
            oa1 = MFMA32(v1, pb[ks], oa1);
        }
    }

    // epilogue: combine pair sums, normalize, write X[((b*2048+q)*16+h)*64 + d]
    float lt = lrun + __shfl_xor(lrun, 32);
    float inv = 1.f / lt;
    const int b = bh >> 4, h = bh & 15;
    ushort_t* dst = X + (((size_t)b * 2048 + q0 + ql) * 16 + h) * 64;
#pragma unroll
    for (int rq = 0; rq < 4; ++rq) {
        ushort_t t0[4], t1[4];
#pragma unroll
        for (int j = 0; j < 4; ++j) {
            t0[j] = f2bf(oa0[rq * 4 + j] * inv);
            t1[j] = f2bf(oa1[rq * 4 + j] * inv);
        }
        *(ushort4*)(dst + rq * 8 + hi * 4)      = *(ushort4*)t0;
        *(ushort4*)(dst + 32 + rq * 8 + hi * 4) = *(ushort4*)t1;
    }
}

// ---------- launcher ----------

extern "C" void kernel_launch(void* const* d_in, const int* in_sizes, int n_in,
                              void* d_out, int out_size, void* d_ws, size_t ws_size,
                              hipStream_t stream) {
    const float* query = (const float*)d_in[0];
    const float* key   = (const float*)d_in[1];
    const float* value = (const float*)d_in[2];
    const float* Wq = (const float*)d_in[3];
    const float* bq = (const float*)d_in[4];
    const float* Wk = (const float*)d_in[5];
    const float* bk = (const float*)d_in[6];
    const float* Wv = (const float*)d_in[7];
    const float* bv = (const float*)d_in[8];
    const float* Wo = (const float*)d_in[9];
    const float* bo = (const float*)d_in[10];
    float* out = (float*)d_out;

    char* ws = (char*)d_ws;
    const size_t MB = 1024 * 1024;
    ushort_t* Wqt = (ushort_t*)(ws + 0 * MB);   // Wq^T,Wk^T,Wv^T contiguous (proj indexes as one)
    ushort_t* Wkt = (ushort_t*)(ws + 2 * MB);
    ushort_t* Wvt = (ushort_t*)(ws + 4 * MB);
    ushort_t* Wot = (ushort_t*)(ws + 6 * MB);
    ushort_t* Xq  = (ushort_t*)(ws + 8 * MB);   // cast(query); later aliased by V^T
    ushort_t* Xk  = (ushort_t*)(ws + 24 * MB);  // cast(key);   later aliased by X(attn out)
    ushort_t* Xv  = (ushort_t*)(ws + 40 * MB);  // cast(value)
    ushort_t* Qp  = (ushort_t*)(ws + 56 * MB);
    ushort_t* Kp  = (ushort_t*)(ws + 72 * MB);
    ushort_t* Vp  = (ushort_t*)(ws + 88 * MB);  // total 104 MB
    ushort_t* Vtp = Xq;   // safe: casts dead after projections
    ushort_t* Xat = Xk;

    const int n8 = 8192 * 1024 / 8;
    castk3<<<dim3(2048), dim3(256), 0, stream>>>(query, key, value, Xq, Xk, Xv, n8);

    wtrans4<<<dim3(16, 16, 4), dim3(256), 0, stream>>>(Wq, Wk, Wv, Wo, Wqt, Wkt, Wvt, Wot);

    proj_qkv<<<dim3(64, 24), dim3(256), 0, stream>>>(Xq, Xk, Xv, Wqt, bq, bk, bv, Qp, Kp, Vp);

    vtrans<<<dim3(64, 32), dim3(256), 0, stream>>>(Vp, Vtp);

    attn<<<dim3(64, 16), dim3(256), 0, stream>>>(Qp, Kp, Vtp, Xat);

    gemm_out<<<dim3(64, 8), dim3(256), 0, stream>>>(Xat, Wot, bo, out);
}